// Round 11
// baseline (2820.702 us; speedup 1.0000x reference)
//
#include <hip/hip_runtime.h>

#define LOWV (-10000.0f)
typedef unsigned long long u64;
typedef __attribute__((ext_vector_type(4))) float f32x4;

__device__ __forceinline__ float sigf(float x){ return 1.0f/(1.0f+expf(-x)); }
__device__ __forceinline__ unsigned fkey(float f){
    unsigned u = __float_as_uint(f);
    return (u & 0x80000000u) ? ~u : (u | 0x80000000u);
}
__device__ __forceinline__ float funkey(unsigned k){
    unsigned u = (k & 0x80000000u) ? (k ^ 0x80000000u) : ~k;
    return __uint_as_float(u);
}
__device__ __forceinline__ float aload_f (const float* p){ return __hip_atomic_load(p, __ATOMIC_RELAXED, __HIP_MEMORY_SCOPE_AGENT); }
__device__ __forceinline__ u64   aload_u64(const u64* p){ return __hip_atomic_load(p, __ATOMIC_RELAXED, __HIP_MEMORY_SCOPE_AGENT); }
__device__ __forceinline__ void  astore_f(float* p, float v){ __hip_atomic_store(p, v, __ATOMIC_RELAXED, __HIP_MEMORY_SCOPE_AGENT); }
__device__ __forceinline__ void  astore_u64(u64* p, u64 v){ __hip_atomic_store(p, v, __ATOMIC_RELAXED, __HIP_MEMORY_SCOPE_AGENT); }
__device__ __forceinline__ float2 bload2(const float* p){
    union { u64 u; float2 f; } c; c.u = aload_u64((const u64*)p); return c.f;
}
__device__ __forceinline__ void bstore2(float* p, float2 v){
    union { u64 u; float2 f; } c; c.f = v; astore_u64((u64*)p, c.u);
}
#define GLD2(d, p) asm volatile("global_load_dwordx2 %0, %1, off sc0 sc1" : "=v"(d) : "v"(p))
#define WAIT0 do{ asm volatile("s_waitcnt vmcnt(0)" ::: "memory"); __builtin_amdgcn_sched_barrier(0); }while(0)

// ---------- transposes: WT[3072][640] (gate-interleaved Wh | Wpred), WoutT[1024][512], WencT[512][1024]
__global__ __launch_bounds__(256) void k_tr(const float* __restrict__ Wh, const float* __restrict__ Wpred,
        const float* __restrict__ Wout, const float* __restrict__ Wenc,
        float* __restrict__ WT, float* __restrict__ WoutT, float* __restrict__ WencT,
        int* __restrict__ cntZ){
    if (blockIdx.x == 0){ for (int i = threadIdx.x; i < 128; i += 256) cntZ[i] = 0; }
    __shared__ float t[64][65];
    int b = blockIdx.x;
    const float* in; float* outp; int R, C, tr, tc, doff, mode;
    if (b < 400)      { in=Wh;    outp=WT;    R=640;  C=2560; tr=b/40;        tc=b%40;        doff=0;    mode=0; }
    else if (b < 480) { b-=400; in=Wpred; outp=WT;    R=640;  C=512;  tr=b/8;  tc=b%8;  doff=2560; mode=1; }
    else if (b < 608) { b-=480; in=Wout;  outp=WoutT; R=512;  C=1024; tr=b>>4; tc=b&15; doff=0;    mode=1; }
    else              { b-=608; in=Wenc;  outp=WencT; R=1024; C=512;  tr=b/8;  tc=b%8;  doff=0;    mode=1; }
    int tx = threadIdx.x & 63, ty0 = threadIdx.x >> 6;
    #pragma unroll
    for (int i = 0; i < 16; ++i){
        int row = i*4 + ty0;
        t[row][tx] = in[(size_t)(tr*64 + row)*C + tc*64 + tx];
    }
    __syncthreads();
    #pragma unroll
    for (int i = 0; i < 16; ++i){
        int row = i*4 + ty0;
        if (mode == 0){
            int c = tc*64 + row;                   // Wh col: g*640 + j -> WT col j*4+g
            int gg2 = c / 640, jj = c - gg2*640;
            outp[(size_t)(jj*4 + gg2)*640 + tr*64 + tx] = t[tx][row];
        } else {
            outp[(size_t)(doff + tc*64 + row)*R + tr*64 + tx] = t[tx][row];
        }
    }
}

// ---------- EWi4[v*640+j] = float4 gates (i,f,g,o) of E@Wi + bi + bh ----------
__global__ __launch_bounds__(256) void k_ewi(const float* __restrict__ E, const float* __restrict__ Wi,
        const float* __restrict__ bi, const float* __restrict__ bh, float4* __restrict__ EWi4){
    int tid = threadIdx.x, lane = tid & 63, wvv = tid >> 6;
    int vb = blockIdx.x / 10, jb = blockIdx.x % 10;   // 1280 blocks
    int j = jb*64 + lane;
    int v0 = vb*8 + wvv*2;
    float acc[2][4];
    #pragma unroll
    for (int i=0;i<2;++i)
        #pragma unroll
        for (int g=0;g<4;++g) acc[i][g] = 0.f;
    for (int k0 = 0; k0 < 512; k0 += 4){
        float ev[2][4];
        #pragma unroll
        for (int i=0;i<2;++i) *(float4*)ev[i] = *(const float4*)(E + (size_t)(v0+i)*512 + k0);
        #pragma unroll
        for (int kk=0;kk<4;++kk){
            const float* wr = Wi + (size_t)(k0+kk)*2560 + j;
            float w0 = wr[0], w1 = wr[640], w2 = wr[1280], w3 = wr[1920];
            #pragma unroll
            for (int i=0;i<2;++i){
                acc[i][0] += ev[i][kk]*w0; acc[i][1] += ev[i][kk]*w1;
                acc[i][2] += ev[i][kk]*w2; acc[i][3] += ev[i][kk]*w3;
            }
        }
    }
    float b0 = bi[j] + bh[j], b1 = bi[640+j] + bh[640+j];
    float b2 = bi[1280+j] + bh[1280+j], b3 = bi[1920+j] + bh[1920+j];
    #pragma unroll
    for (int i=0;i<2;++i)
        EWi4[(size_t)(v0+i)*640 + j] = make_float4(acc[i][0]+b0, acc[i][1]+b1, acc[i][2]+b2, acc[i][3]+b3);
}

// ---------- persistent decode: 8 independent groups x 32 blocks, group-local sync only ----------
__global__ __launch_bounds__(512, 2) void mega(
    const float* __restrict__ enc, const int* __restrict__ lens, const float* __restrict__ bj,
    const float* __restrict__ WT, const float* __restrict__ WoutT, const float* __restrict__ WencT,
    const float4* __restrict__ EWi4,
    float* __restrict__ hT, float* __restrict__ encPT, float* __restrict__ jointT,
    u64* __restrict__ packedP, float* __restrict__ sumexpP,
    int* __restrict__ cntZ, float* __restrict__ out)
{
    __shared__ float sH[10240];     // h [k=640][16 rows]
    __shared__ float sJ[8192];      // joint [512][16]
    __shared__ float sG[1536];      // gates [96 local cols][16]  (persists P1 -> P3)
    __shared__ float sC[384];       // c-state [24 j][16]          (persists whole kernel)
    __shared__ u64   kxw[128];
    __shared__ float exw[128];
    __shared__ float sBJ[96];
    __shared__ int sAct[16], sEncT[16], sNEm[16], sLen[16], sTok[16], sUpd[16], sAdv[16];

    const int bid = blockIdx.x, tid = threadIdx.x, lane = tid & 63, wv = tid >> 6;
    const int G = bid >> 5, GB = bid & 31, RB = G*16;
    const int jcnt = (GB <= 25) ? 24 : (GB == 26 ? 16 : 0);
    float* hTg = hT + (size_t)G*20480;
    float* jTg = jointT + (size_t)G*8192;
    float* ePg = encPT + (size_t)G*8192;
    u64*   pkg = packedP + (size_t)G*768*8;
    float* seg = sumexpP + (size_t)G*768*16;
    int ep = 0;
    float scReg = 0.f;

    auto gsync = [&](){
        asm volatile("s_waitcnt vmcnt(0)" ::: "memory");
        __syncthreads();
        ++ep;
        if (tid == 0){
            __hip_atomic_fetch_add(&cntZ[G*16], 1, __ATOMIC_RELAXED, __HIP_MEMORY_SCOPE_AGENT);
            while (__hip_atomic_load(&cntZ[G*16], __ATOMIC_RELAXED, __HIP_MEMORY_SCOPE_AGENT) < ep*32)
                __builtin_amdgcn_s_sleep(2);
        }
        __syncthreads();
    };

    // ---- prologue (all group-local) ----
    if (tid < 96){ int col = GB*96 + tid; sBJ[tid] = (col >= 2560) ? bj[col - 2560] : 0.f; }
    if (tid < 16){ sAct[tid] = 1; sEncT[tid] = 0; sNEm[tid] = 0; sLen[tid] = lens[RB + tid]; }
    if (tid < 24){
        astore_u64(&pkg[(size_t)(GB*24 + tid)*8], 0ull);
        astore_f(&seg[(size_t)(GB*24 + tid)*16], 0.f);
    }
    if (tid < jcnt*16){
        int j = tid >> 4, r = tid & 15, jg = GB*24 + j;
        float4 e0 = EWi4[jg];
        float c0v = sigf(e0.x)*tanhf(e0.z);
        float h0v = tanhf(c0v)*sigf(e0.w);
        sC[j*16 + r] = c0v;
        astore_f(&hTg[jg*16 + r], h0v);
    }
    {   // frame-0 encoder projection: 16 own cols x 16 rows, K=1024 split over kq
        int ec = tid >> 5, r = (tid >> 1) & 15, kq = tid & 1;
        const float* ep_ = enc + (size_t)(RB + r)*160*1024 + kq*512;
        const float* wp_ = WencT + (size_t)(GB*16 + ec)*1024 + kq*512;
        float acc = 0.f;
        #pragma unroll 8
        for (int k = 0; k < 512; ++k) acc += ep_[k]*wp_[k];
        acc += __shfl_xor(acc, 1, 64);
        if (kq == 0) astore_f(&ePg[(size_t)(GB*16 + ec)*16 + r], acc);
    }
    gsync();   // B0

    for (int s = 0; s < 48; ++s){
        const int p = s & 1, w = 1 - p;

        // ---- stage sH (40KB bypass, batched) ----
        {
            const u64* hb = (const u64*)(hTg + (size_t)p*10240);
            u64 hbuf[10];
            #pragma unroll
            for (int i = 0; i < 10; ++i) GLD2(hbuf[i], hb + tid + i*512);
            WAIT0;
            #pragma unroll
            for (int i = 0; i < 10; ++i) ((u64*)sH)[tid + i*512] = hbuf[i];
        }
        __syncthreads();

        // ===== P1: 96 W-cols/block (gates stay in sG; joint -> jointT bypass) =====
        if (tid < 384){
            int c96 = tid >> 2, rq = tid & 3;
            int col = GB*96 + c96;
            const float* wp = WT + (size_t)col*640;
            f32x4 acc = {0.f, 0.f, 0.f, 0.f};
            #pragma unroll 4
            for (int k = 0; k < 640; ++k){
                float wval = wp[k];
                f32x4 h4 = *(const f32x4*)(sH + k*16 + rq*4);
                acc += h4 * wval;
            }
            if (col < 2560){
                *(f32x4*)(sG + c96*16 + rq*4) = acc;
            } else {
                int cj = col - 2560;
                float2 e01 = bload2(&ePg[(size_t)cj*16 + rq*4]);
                float2 e23 = bload2(&ePg[(size_t)cj*16 + rq*4 + 2]);
                float bjv = sBJ[c96];
                bstore2(&jTg[(size_t)cj*16 + rq*4],
                        make_float2(tanhf(acc.x + e01.x + bjv), tanhf(acc.y + e01.y + bjv)));
                bstore2(&jTg[(size_t)cj*16 + rq*4 + 2],
                        make_float2(tanhf(acc.z + e23.x + bjv), tanhf(acc.w + e23.y + bjv)));
            }
        }
        gsync();   // B1

        // ---- stage sJ (32KB bypass) ----
        {
            const u64* jb = (const u64*)jTg;
            u64 jbuf[8];
            #pragma unroll
            for (int i = 0; i < 8; ++i) GLD2(jbuf[i], jb + tid + i*512);
            WAIT0;
            #pragma unroll
            for (int i = 0; i < 8; ++i) ((u64*)sJ)[tid + i*512] = jbuf[i];
        }
        __syncthreads();

        // ===== P2: logits 32 cols/block, wave-shuffle argmax, 16 padded atomics =====
        {
            int c32 = tid >> 4, r = tid & 15;
            int col = GB*32 + c32;
            const float* wp2 = WoutT + (size_t)col*512;
            float acc = 0.f;
            #pragma unroll 8
            for (int k = 0; k < 512; ++k) acc += sJ[k*16 + r] * wp2[k];
            float es = expf(acc);
            bool force = sNEm[r] >= 2;
            int idx; float va;
            if (col == 0){ idx = 1024; va = acc; }
            else { idx = col; va = force ? LOWV : acc; }
            unsigned kh2 = fkey(va), kl2 = (unsigned)(2047 - idx);
            #pragma unroll
            for (int off = 16; off <= 32; off <<= 1){
                unsigned ol = __shfl_xor(kl2, off, 64);
                unsigned oh = __shfl_xor(kh2, off, 64);
                float oe = __shfl_xor(es, off, 64);
                if (oh > kh2 || (oh == kh2 && ol > kl2)){ kh2 = oh; kl2 = ol; }
                es += oe;
            }
            if (lane < 16){
                kxw[wv*16 + lane] = ((u64)kh2 << 32) | kl2;
                exw[wv*16 + lane] = es;
            }
        }
        __syncthreads();
        if (tid < 16){
            u64 m = kxw[tid]; float es2 = exw[tid];
            #pragma unroll
            for (int q2 = 1; q2 < 8; ++q2){
                u64 o = kxw[q2*16 + tid]; if (o > m) m = o;
                es2 += exw[q2*16 + tid];
            }
            atomicMax(&pkg[((size_t)s*16 + tid)*8], m);
            atomicAdd(&seg[((size_t)s*16 + tid)*16], es2);
        }
        gsync();   // B2

        // ===== P3: state machine | LSTM pointwise | lazy enc-proj =====
        if (tid < 16){
            int r = tid;
            u64 pk = aload_u64(&pkg[((size_t)s*16 + r)*8]);
            int tok = 2047 - (int)(unsigned)(pk & 0xffffffffu);
            int act = sAct[r];
            int isb = (tok == 1024);
            sTok[r] = tok;
            sUpd[r] = act && !isb;
            int et = sEncT[r], ne = sNEm[r], act_n = act, adv = -1;
            if (act){
                et += isb;
                ne = isb ? 0 : ne + 1;
                act_n = (et < sLen[r]) ? 1 : 0;
                if (isb && act_n) adv = et;
            }
            sAdv[r] = adv;
            sAct[r] = act_n; sEncT[r] = et; sNEm[r] = ne;
            if (GB == 31){
                int tok_out = 1024;
                if (act){
                    float val = funkey((unsigned)(pk >> 32));
                    float se = aload_f(&seg[((size_t)s*16 + r)*16]);
                    scReg += val - logf(se);
                    tok_out = (act_n || isb) ? tok : 1024;
                }
                out[(size_t)(RB + r)*48 + s] = (float)tok_out;
                if (s == 47) out[6144 + RB + r] = scReg;
            }
        }
        __syncthreads();
        if (tid < jcnt*16){
            int j = tid >> 4, r = tid & 15, jg = GB*24 + j;
            float hnew;
            if (sUpd[r]){
                int tok = sTok[r];
                float4 ew = EWi4[(size_t)tok*640 + jg];
                float gi = sG[(j*4+0)*16 + r] + ew.x;
                float gf = sG[(j*4+1)*16 + r] + ew.y;
                float gv = sG[(j*4+2)*16 + r] + ew.z;
                float go = sG[(j*4+3)*16 + r] + ew.w;
                float cold = sC[j*16 + r];
                float cn = sigf(gf)*cold + sigf(gi)*tanhf(gv);
                hnew = tanhf(cn)*sigf(go);
                sC[j*16 + r] = cn;
            } else {
                hnew = sH[jg*16 + r];
            }
            astore_f(&hTg[(size_t)w*10240 + jg*16 + r], hnew);
        }
        {
            int ec = tid >> 5, r = (tid >> 1) & 15, kq = tid & 1;
            int t = sAdv[r];
            float acc = 0.f;
            if (t >= 0){
                const float* ep_ = enc + ((size_t)(RB + r)*160 + t)*1024 + kq*512;
                const float* wp_ = WencT + (size_t)(GB*16 + ec)*1024 + kq*512;
                #pragma unroll 8
                for (int k = 0; k < 512; ++k) acc += ep_[k]*wp_[k];
            }
            acc += __shfl_xor(acc, 1, 64);
            if (kq == 0 && t >= 0) astore_f(&ePg[(size_t)(GB*16 + ec)*16 + r], acc);
        }
        gsync();   // B3
    }
}

extern "C" void kernel_launch(void* const* d_in, const int* in_sizes, int n_in,
                              void* d_out, int out_size, void* d_ws, size_t ws_size,
                              hipStream_t stream) {
    const float* enc   = (const float*)d_in[0];
    const int*   lens  = (const int*)  d_in[1];
    const float* E     = (const float*)d_in[3];
    const float* Wi    = (const float*)d_in[4];
    const float* Wh    = (const float*)d_in[5];
    const float* bi    = (const float*)d_in[6];
    const float* bh    = (const float*)d_in[7];
    const float* Wenc  = (const float*)d_in[8];
    const float* Wpred = (const float*)d_in[9];
    const float* bj    = (const float*)d_in[10];
    const float* Wout  = (const float*)d_in[11];
    float* out = (float*)d_out;

    char* base = (char*)d_ws;
    size_t off = 0;
    auto carve = [&](size_t bytes) -> void* {
        void* pp = base + off;
        off += (bytes + 255) & ~(size_t)255;
        return pp;
    };
    float*  WT    = (float*)carve((size_t)3072*640*4);
    float*  WoutT = (float*)carve((size_t)1024*512*4);
    float*  WencT = (float*)carve((size_t)512*1024*4);
    float4* EWi4  = (float4*)carve((size_t)1024*640*16);
    float*  hT    = (float*)carve((size_t)8*20480*4);
    float*  encPT = (float*)carve((size_t)8*8192*4);
    float*  jointT= (float*)carve((size_t)8*8192*4);
    u64*    packedP = (u64*)carve((size_t)8*768*8*8);
    float*  sumexpP = (float*)carve((size_t)8*768*16*4);
    int*    cntZ  = (int*)carve(128*4);
    (void)ws_size; (void)in_sizes; (void)n_in; (void)out_size;

    k_tr <<<736,  256, 0, stream>>>(Wh, Wpred, Wout, Wenc, WT, WoutT, WencT, cntZ);
    k_ewi<<<1280, 256, 0, stream>>>(E, Wi, bi, bh, EWi4);
    mega <<<256, 512, 0, stream>>>(enc, lens, bj, WT, WoutT, WencT, EWi4,
                                   hT, encPT, jointT, packedP, sumexpP, cntZ, out);
}